// Round 1
// baseline (3160.299 us; speedup 1.0000x reference)
//
#include <hip/hip_runtime.h>
#include <hip/hip_bf16.h>

#define D_IN  128
#define D_HID 256

typedef __bf16 bf16x8 __attribute__((ext_vector_type(8)));
typedef float  f32x4  __attribute__((ext_vector_type(4)));

__device__ __forceinline__ unsigned short f2bf(float f) {
    unsigned u = __float_as_uint(f);
    u += 0x7FFFu + ((u >> 16) & 1u);   // RNE
    return (unsigned short)(u >> 16);
}
__device__ __forceinline__ uint2 pack4(float4 v) {
    unsigned lo = (unsigned)f2bf(v.x) | ((unsigned)f2bf(v.y) << 16);
    unsigned hi = (unsigned)f2bf(v.z) | ((unsigned)f2bf(v.w) << 16);
    return make_uint2(lo, hi);
}

// Detect whether edge_index is int64 (hi dwords of first 64 entries all zero) or int32.
__global__ void detect_idx_dtype(const int* __restrict__ ei32, int* __restrict__ flag) {
    if (threadIdx.x == 0 && blockIdx.x == 0) {
        int is64 = 1;
        for (int i = 0; i < 64; ++i) {
            if (ei32[2 * i + 1] != 0) { is64 = 0; break; }
        }
        *flag = is64;
    }
}

// One edge handled by 32 threads (float4 each): gather x[src], atomically add into agg[tgt].
__global__ void scatter_edges(const float* __restrict__ x, const void* __restrict__ ei,
                              float* __restrict__ agg, float* __restrict__ deg,
                              const int* __restrict__ flag, int E) {
    int gid = blockIdx.x * blockDim.x + threadIdx.x;
    int e = gid >> 5;
    int q = gid & 31;
    if (e >= E) return;
    long long s, t;
    if (*flag) {
        const long long* p = (const long long*)ei;
        s = p[e]; t = p[E + e];
    } else {
        const int* p = (const int*)ei;
        s = p[e]; t = p[E + e];
    }
    float4 v = ((const float4*)x)[s * 32 + q];
    float* dst = agg + t * D_IN + q * 4;
    atomicAdd(dst + 0, v.x);
    atomicAdd(dst + 1, v.y);
    atomicAdd(dst + 2, v.z);
    atomicAdd(dst + 3, v.w);
    if (q == 0) atomicAdd(deg + t, 1.0f);
}

// Fused GEMM: C[m][j] = sum_k A[m][k] * B[j][k], A=[x | agg/deg], B=[Wr2 | Wl2],
// then colsum_m relu(C + bias) -> per-block partials (no global atomic contention).
// Tile: 128(m) x 128(n) per block, 4 waves each 64x64, K=256 in 4 chunks of 64.
__global__ __launch_bounds__(256)
void gemm_pool(const float* __restrict__ x, const float* __restrict__ agg,
               const float* __restrict__ deg,
               const float* __restrict__ Wr2, const float* __restrict__ Wl2,
               const float* __restrict__ bias2,
               float* __restrict__ part, int M, int NMB) {
    __shared__ unsigned short As[128][72];   // 64 bf16 cols + 8 pad (2-way bank alias: free)
    __shared__ unsigned short Bs[128][72];
    __shared__ float pool_l[128];

    const int tid = threadIdx.x;
    const int blk_m = blockIdx.x, blk_n = blockIdx.y;
    const long mbase = (long)blk_m * 128;

    const float4* x4   = (const float4*)x;
    const float4* agg4 = (const float4*)agg;
    const float4* wr4  = (const float4*)Wr2;
    const float4* wl4  = (const float4*)Wl2;

    const int lane = tid & 63;
    const int wave = tid >> 6;
    const int wm = wave >> 1, wn = wave & 1;
    const int lrow = lane & 15;
    const int quad = lane >> 4;

    const int sc = tid & 15;   // float4 column within 64-float chunk
    const int sr = tid >> 4;   // base row (0..15)

    f32x4 acc[4][4] = {};

    for (int kc = 0; kc < 4; ++kc) {
        // ---- stage A and B chunk (cols kc*64 .. kc*64+63) as bf16 into LDS ----
        #pragma unroll
        for (int it = 0; it < 8; ++it) {
            const int rowl = sr + it * 16;
            // A row
            const long m = mbase + rowl;
            float4 v = make_float4(0.f, 0.f, 0.f, 0.f);
            if (m < M) {
                if (kc < 2) {
                    v = x4[m * 32 + kc * 16 + sc];
                } else {
                    v = agg4[m * 32 + (kc - 2) * 16 + sc];
                    const float rd = 1.0f / fmaxf(deg[m], 1.0f);
                    v.x *= rd; v.y *= rd; v.z *= rd; v.w *= rd;
                }
            }
            *(uint2*)&As[rowl][sc * 4] = pack4(v);
            // B row (output feature j)
            const int j = blk_n * 128 + rowl;
            float4 w = (kc < 2) ? wr4[j * 32 + kc * 16 + sc]
                                : wl4[j * 32 + (kc - 2) * 16 + sc];
            *(uint2*)&Bs[rowl][sc * 4] = pack4(w);
        }
        __syncthreads();

        // ---- MFMA: 2 k-steps of 32 ----
        #pragma unroll
        for (int ks = 0; ks < 2; ++ks) {
            const int k0 = ks * 32 + quad * 8;
            bf16x8 a[4], b[4];
            #pragma unroll
            for (int i = 0; i < 4; ++i)
                a[i] = *(const bf16x8*)&As[wm * 64 + i * 16 + lrow][k0];
            #pragma unroll
            for (int t = 0; t < 4; ++t)
                b[t] = *(const bf16x8*)&Bs[wn * 64 + t * 16 + lrow][k0];
            #pragma unroll
            for (int i = 0; i < 4; ++i)
                #pragma unroll
                for (int t = 0; t < 4; ++t)
                    acc[i][t] = __builtin_amdgcn_mfma_f32_16x16x32_bf16(a[i], b[t], acc[i][t], 0, 0, 0);
        }
        __syncthreads();
    }

    // ---- epilogue: relu(+bias), column-sum over valid rows, block partials ----
    if (tid < 128) pool_l[tid] = 0.f;
    __syncthreads();

    #pragma unroll
    for (int t = 0; t < 4; ++t) {
        const int jl = wn * 64 + t * 16 + (lane & 15);
        const int jg = blk_n * 128 + jl;
        const float bv = bias2[jg];
        float s = 0.f;
        #pragma unroll
        for (int i = 0; i < 4; ++i) {
            const long rbase = mbase + wm * 64 + i * 16 + quad * 4;
            #pragma unroll
            for (int r = 0; r < 4; ++r) {
                float h = acc[i][t][r] + bv;
                h = fmaxf(h, 0.f);
                if (rbase + r < M) s += h;
            }
        }
        s += __shfl_xor(s, 16);
        s += __shfl_xor(s, 32);
        if (quad == 0) atomicAdd(&pool_l[jl], s);
    }
    __syncthreads();
    if (tid < 128) part[((long)blk_n * NMB + blk_m) * 128 + tid] = pool_l[tid];
}

// Reduce partials -> pooled mean -> MLP head -> log_softmax. One block, 256 threads.
__global__ void head_kernel(const float* __restrict__ part,
                            const float* __restrict__ W1, const float* __restrict__ b1,
                            const float* __restrict__ W2, const float* __restrict__ b2,
                            float* __restrict__ out, int NMB, int M) {
    __shared__ float pooled_s[256];
    __shared__ float z1_s[256];
    __shared__ float z2_s[10];
    const int j = threadIdx.x;

    float s = 0.f;
    const float* p = part + ((long)(j >> 7) * NMB) * 128 + (j & 127);
    for (int b = 0; b < NMB; ++b) s += p[b * 128];
    pooled_s[j] = s / (float)M;
    __syncthreads();

    float a = b1[j];
    for (int k = 0; k < 256; ++k) a += W1[j * 256 + k] * pooled_s[k];
    z1_s[j] = fmaxf(a, 0.f);
    __syncthreads();

    if (j < 10) {
        float a2 = b2[j];
        for (int k = 0; k < 256; ++k) a2 += W2[j * 256 + k] * z1_s[k];
        z2_s[j] = a2;
    }
    __syncthreads();

    if (j == 0) {
        float mx = z2_s[0];
        for (int c = 1; c < 10; ++c) mx = fmaxf(mx, z2_s[c]);
        float se = 0.f;
        for (int c = 0; c < 10; ++c) se += expf(z2_s[c] - mx);
        const float ls = logf(se);
        for (int c = 0; c < 10; ++c) out[c] = z2_s[c] - mx - ls;
    }
}

extern "C" void kernel_launch(void* const* d_in, const int* in_sizes, int n_in,
                              void* d_out, int out_size, void* d_ws, size_t ws_size,
                              hipStream_t stream) {
    const float* x    = (const float*)d_in[0];
    const void*  ei   = d_in[1];
    const float* Wl   = (const float*)d_in[2];
    const float* Wr   = (const float*)d_in[3];
    const float* bias = (const float*)d_in[4];
    const float* W1   = (const float*)d_in[5];
    const float* b1   = (const float*)d_in[6];
    const float* W2   = (const float*)d_in[7];
    const float* b2   = (const float*)d_in[8];
    float* out = (float*)d_out;

    const int M = in_sizes[0] / D_IN;       // 100000 nodes
    const int E = in_sizes[1] / 2;          // 1.6M edges
    const int L = in_sizes[4] / D_HID;      // 3 layers
    const int NMB = (M + 127) / 128;        // m-blocks (782)

    // Only the LAST layer matters (h is overwritten each loop iteration).
    const float* Wl2   = Wl + (long)(L - 1) * D_HID * D_IN;
    const float* Wr2   = Wr + (long)(L - 1) * D_HID * D_IN;
    const float* bias2 = bias + (long)(L - 1) * D_HID;

    // workspace layout (floats): agg[M*128] | deg[M] | part[2*NMB*128] | flag
    float* ws  = (float*)d_ws;
    float* agg = ws;
    float* deg = ws + (long)M * D_IN;
    float* part = deg + M;
    int*   flag = (int*)(part + (long)2 * NMB * 128);

    // zero agg + deg (atomics accumulate into them)
    hipMemsetAsync(d_ws, 0, ((long)M * D_IN + M) * sizeof(float), stream);

    detect_idx_dtype<<<1, 64, 0, stream>>>((const int*)ei, flag);

    const long nthreads = (long)E * 32;
    scatter_edges<<<(int)((nthreads + 255) / 256), 256, 0, stream>>>(x, ei, agg, deg, flag, E);

    dim3 g(NMB, 2);
    gemm_pool<<<g, 256, 0, stream>>>(x, agg, deg, Wr2, Wl2, bias2, part, M, NMB);

    head_kernel<<<1, 256, 0, stream>>>(part, W1, b1, W2, b2, out, NMB, M);
}

// Round 2
// 917.956 us; speedup vs baseline: 3.4428x; 3.4428x over previous
//
#include <hip/hip_runtime.h>
#include <hip/hip_bf16.h>

#define D_IN  128
#define D_HID 256

typedef __bf16 bf16x8 __attribute__((ext_vector_type(8)));
typedef float  f32x4  __attribute__((ext_vector_type(4)));

__device__ __forceinline__ unsigned short f2bf(float f) {
    unsigned u = __float_as_uint(f);
    u += 0x7FFFu + ((u >> 16) & 1u);   // RNE
    return (unsigned short)(u >> 16);
}
__device__ __forceinline__ uint2 pack4(float4 v) {
    unsigned lo = (unsigned)f2bf(v.x) | ((unsigned)f2bf(v.y) << 16);
    unsigned hi = (unsigned)f2bf(v.z) | ((unsigned)f2bf(v.w) << 16);
    return make_uint2(lo, hi);
}

// Detect whether edge_index is int64 (hi dwords of first 64 entries all zero) or int32.
__global__ void detect_idx_dtype(const int* __restrict__ ei32, int* __restrict__ flag) {
    if (threadIdx.x == 0 && blockIdx.x == 0) {
        int is64 = 1;
        for (int i = 0; i < 64; ++i) {
            if (ei32[2 * i + 1] != 0) { is64 = 0; break; }
        }
        *flag = is64;
    }
}

// Count in-degree of each target node (int atomics into 400KB array - L2 resident).
__global__ void count_edges(const void* __restrict__ ei, const int* __restrict__ flag,
                            int* __restrict__ cnt, int E) {
    int e = blockIdx.x * blockDim.x + threadIdx.x;
    if (e >= E) return;
    int t;
    if (*flag) t = (int)((const long long*)ei)[E + e];
    else       t = ((const int*)ei)[E + e];
    atomicAdd(&cnt[t], 1);
}

// Single-block exclusive scan of cnt[M] -> rowptr[M+1] and cursor[M].
__global__ __launch_bounds__(1024)
void scan_kernel(const int* __restrict__ cnt, int* __restrict__ rowptr,
                 int* __restrict__ cursor, int M) {
    __shared__ int sums[1024];
    const int t = threadIdx.x;
    const int chunk = (M + 1023) / 1024;
    const int beg = t * chunk;
    const int end = min(beg + chunk, M);
    int s = 0;
    for (int i = beg; i < end; ++i) s += cnt[i];
    sums[t] = s;
    __syncthreads();
    for (int off = 1; off < 1024; off <<= 1) {
        int v = (t >= off) ? sums[t - off] : 0;
        __syncthreads();
        sums[t] += v;
        __syncthreads();
    }
    int prefix = (t == 0) ? 0 : sums[t - 1];
    for (int i = beg; i < end; ++i) {
        int c = cnt[i];
        rowptr[i] = prefix;
        cursor[i] = prefix;
        prefix += c;
    }
    if (t == 1023) rowptr[M] = sums[1023];
}

// Scatter edge source ids into CSR buckets (int atomics on cursor, L2 resident).
__global__ void fill_csr(const void* __restrict__ ei, const int* __restrict__ flag,
                         int* __restrict__ cursor, int* __restrict__ csr_src, int E) {
    int e = blockIdx.x * blockDim.x + threadIdx.x;
    if (e >= E) return;
    int s, t;
    if (*flag) {
        const long long* p = (const long long*)ei;
        s = (int)p[e]; t = (int)p[E + e];
    } else {
        const int* p = (const int*)ei;
        s = p[e]; t = p[E + e];
    }
    int pos = atomicAdd(&cursor[t], 1);
    csr_src[pos] = s;
}

// One wave per node: gather+accumulate x[src] rows, normalize by degree, store agg.
__global__ __launch_bounds__(256)
void gather_nodes(const float* __restrict__ x, const int* __restrict__ rowptr,
                  const int* __restrict__ csr_src, float* __restrict__ agg, int M) {
    const int wave = threadIdx.x >> 6;
    const int lane = threadIdx.x & 63;
    const int node = blockIdx.x * 4 + wave;
    if (node >= M) return;
    const int beg = rowptr[node], end = rowptr[node + 1];
    const float2* x2 = (const float2*)x;
    float ax = 0.f, ay = 0.f;
    int i = beg;
    // 2-way unroll for load ILP
    for (; i + 2 <= end; i += 2) {
        int s0 = csr_src[i], s1 = csr_src[i + 1];
        float2 v0 = x2[(long)s0 * 64 + lane];
        float2 v1 = x2[(long)s1 * 64 + lane];
        ax += v0.x + v1.x; ay += v0.y + v1.y;
    }
    if (i < end) {
        float2 v = x2[(long)csr_src[i] * 64 + lane];
        ax += v.x; ay += v.y;
    }
    const float rd = 1.0f / fmaxf((float)(end - beg), 1.0f);
    ((float2*)agg)[(long)node * 64 + lane] = make_float2(ax * rd, ay * rd);
}

// Fused GEMM: C[m][j] = sum_k A[m][k]*B[j][k], A=[x | agg], B=[Wr2 | Wl2],
// then colsum_m relu(C + bias) -> per-block partials.
__global__ __launch_bounds__(256)
void gemm_pool(const float* __restrict__ x, const float* __restrict__ agg,
               const float* __restrict__ Wr2, const float* __restrict__ Wl2,
               const float* __restrict__ bias2,
               float* __restrict__ part, int M, int NMB) {
    __shared__ unsigned short As[128][72];
    __shared__ unsigned short Bs[128][72];
    __shared__ float pool_l[128];

    const int tid = threadIdx.x;
    const int blk_m = blockIdx.x, blk_n = blockIdx.y;
    const long mbase = (long)blk_m * 128;

    const float4* x4   = (const float4*)x;
    const float4* agg4 = (const float4*)agg;
    const float4* wr4  = (const float4*)Wr2;
    const float4* wl4  = (const float4*)Wl2;

    const int lane = tid & 63;
    const int wave = tid >> 6;
    const int wm = wave >> 1, wn = wave & 1;
    const int lrow = lane & 15;
    const int quad = lane >> 4;

    const int sc = tid & 15;
    const int sr = tid >> 4;

    f32x4 acc[4][4] = {};

    for (int kc = 0; kc < 4; ++kc) {
        #pragma unroll
        for (int it = 0; it < 8; ++it) {
            const int rowl = sr + it * 16;
            const long m = mbase + rowl;
            float4 v = make_float4(0.f, 0.f, 0.f, 0.f);
            if (m < M) {
                v = (kc < 2) ? x4[m * 32 + kc * 16 + sc]
                             : agg4[m * 32 + (kc - 2) * 16 + sc];
            }
            *(uint2*)&As[rowl][sc * 4] = pack4(v);
            const int j = blk_n * 128 + rowl;
            float4 w = (kc < 2) ? wr4[j * 32 + kc * 16 + sc]
                                : wl4[j * 32 + (kc - 2) * 16 + sc];
            *(uint2*)&Bs[rowl][sc * 4] = pack4(w);
        }
        __syncthreads();

        #pragma unroll
        for (int ks = 0; ks < 2; ++ks) {
            const int k0 = ks * 32 + quad * 8;
            bf16x8 a[4], b[4];
            #pragma unroll
            for (int i = 0; i < 4; ++i)
                a[i] = *(const bf16x8*)&As[wm * 64 + i * 16 + lrow][k0];
            #pragma unroll
            for (int t = 0; t < 4; ++t)
                b[t] = *(const bf16x8*)&Bs[wn * 64 + t * 16 + lrow][k0];
            #pragma unroll
            for (int i = 0; i < 4; ++i)
                #pragma unroll
                for (int t = 0; t < 4; ++t)
                    acc[i][t] = __builtin_amdgcn_mfma_f32_16x16x32_bf16(a[i], b[t], acc[i][t], 0, 0, 0);
        }
        __syncthreads();
    }

    if (tid < 128) pool_l[tid] = 0.f;
    __syncthreads();

    #pragma unroll
    for (int t = 0; t < 4; ++t) {
        const int jl = wn * 64 + t * 16 + (lane & 15);
        const int jg = blk_n * 128 + jl;
        const float bv = bias2[jg];
        float s = 0.f;
        #pragma unroll
        for (int i = 0; i < 4; ++i) {
            const long rbase = mbase + wm * 64 + i * 16 + quad * 4;
            #pragma unroll
            for (int r = 0; r < 4; ++r) {
                float h = acc[i][t][r] + bv;
                h = fmaxf(h, 0.f);
                if (rbase + r < M) s += h;
            }
        }
        s += __shfl_xor(s, 16);
        s += __shfl_xor(s, 32);
        if (quad == 0) atomicAdd(&pool_l[jl], s);
    }
    __syncthreads();
    if (tid < 128) part[((long)blk_n * NMB + blk_m) * 128 + tid] = pool_l[tid];
}

// Reduce partials -> pooled mean -> MLP head -> log_softmax. One block, 256 threads.
__global__ void head_kernel(const float* __restrict__ part,
                            const float* __restrict__ W1, const float* __restrict__ b1,
                            const float* __restrict__ W2, const float* __restrict__ b2,
                            float* __restrict__ out, int NMB, int M) {
    __shared__ float pooled_s[256];
    __shared__ float z1_s[256];
    __shared__ float z2_s[10];
    const int j = threadIdx.x;

    float s = 0.f;
    const float* p = part + ((long)(j >> 7) * NMB) * 128 + (j & 127);
    for (int b = 0; b < NMB; ++b) s += p[b * 128];
    pooled_s[j] = s / (float)M;
    __syncthreads();

    float a = b1[j];
    for (int k = 0; k < 256; ++k) a += W1[j * 256 + k] * pooled_s[k];
    z1_s[j] = fmaxf(a, 0.f);
    __syncthreads();

    if (j < 10) {
        float a2 = b2[j];
        for (int k = 0; k < 256; ++k) a2 += W2[j * 256 + k] * z1_s[k];
        z2_s[j] = a2;
    }
    __syncthreads();

    if (j == 0) {
        float mx = z2_s[0];
        for (int c = 1; c < 10; ++c) mx = fmaxf(mx, z2_s[c]);
        float se = 0.f;
        for (int c = 0; c < 10; ++c) se += expf(z2_s[c] - mx);
        const float ls = logf(se);
        for (int c = 0; c < 10; ++c) out[c] = z2_s[c] - mx - ls;
    }
}

extern "C" void kernel_launch(void* const* d_in, const int* in_sizes, int n_in,
                              void* d_out, int out_size, void* d_ws, size_t ws_size,
                              hipStream_t stream) {
    const float* x    = (const float*)d_in[0];
    const void*  ei   = d_in[1];
    const float* Wl   = (const float*)d_in[2];
    const float* Wr   = (const float*)d_in[3];
    const float* bias = (const float*)d_in[4];
    const float* W1   = (const float*)d_in[5];
    const float* b1   = (const float*)d_in[6];
    const float* W2   = (const float*)d_in[7];
    const float* b2   = (const float*)d_in[8];
    float* out = (float*)d_out;

    const int M = in_sizes[0] / D_IN;       // 100000 nodes
    const int E = in_sizes[1] / 2;          // 1.6M edges
    const int L = in_sizes[4] / D_HID;      // 3 layers
    const int NMB = (M + 127) / 128;

    // Only the LAST layer matters (h is overwritten each loop iteration).
    const float* Wl2   = Wl + (long)(L - 1) * D_HID * D_IN;
    const float* Wr2   = Wr + (long)(L - 1) * D_HID * D_IN;
    const float* bias2 = bias + (long)(L - 1) * D_HID;

    // workspace layout: agg[M*128]f | part[2*NMB*128]f | cnt[M]i | rowptr[M+1]i
    //                   | cursor[M]i | csr[E]i | flag i
    float* ws     = (float*)d_ws;
    float* agg    = ws;
    float* part   = agg + (long)M * D_IN;
    int*   cnt    = (int*)(part + (long)2 * NMB * 128);
    int*   rowptr = cnt + M;
    int*   cursor = rowptr + M + 1;
    int*   csr    = cursor + M;
    int*   flag   = csr + E;

    detect_idx_dtype<<<1, 64, 0, stream>>>((const int*)ei, flag);
    hipMemsetAsync(cnt, 0, (size_t)M * sizeof(int), stream);

    count_edges<<<(E + 255) / 256, 256, 0, stream>>>(ei, flag, cnt, E);
    scan_kernel<<<1, 1024, 0, stream>>>(cnt, rowptr, cursor, M);
    fill_csr<<<(E + 255) / 256, 256, 0, stream>>>(ei, flag, cursor, csr, E);
    gather_nodes<<<(M + 3) / 4, 256, 0, stream>>>(x, rowptr, csr, agg, M);

    dim3 g(NMB, 2);
    gemm_pool<<<g, 256, 0, stream>>>(x, agg, Wr2, Wl2, bias2, part, M, NMB);

    head_kernel<<<1, 256, 0, stream>>>(part, W1, b1, W2, b2, out, NMB, M);
}

// Round 3
// 713.153 us; speedup vs baseline: 4.4314x; 1.2872x over previous
//
#include <hip/hip_runtime.h>
#include <hip/hip_bf16.h>

#define D_IN  128
#define D_HID 256

typedef __bf16 bf16x8 __attribute__((ext_vector_type(8)));
typedef float  f32x4  __attribute__((ext_vector_type(4)));

__device__ __forceinline__ unsigned short f2bf(float f) {
    unsigned u = __float_as_uint(f);
    u += 0x7FFFu + ((u >> 16) & 1u);   // RNE
    return (unsigned short)(u >> 16);
}
__device__ __forceinline__ uint2 pack4(float4 v) {
    unsigned lo = (unsigned)f2bf(v.x) | ((unsigned)f2bf(v.y) << 16);
    unsigned hi = (unsigned)f2bf(v.z) | ((unsigned)f2bf(v.w) << 16);
    return make_uint2(lo, hi);
}

// Detect whether edge_index is int64 (hi dwords of first 64 entries all zero) or int32.
__global__ void detect_idx_dtype(const int* __restrict__ ei32, int* __restrict__ flag) {
    if (threadIdx.x == 0 && blockIdx.x == 0) {
        int is64 = 1;
        for (int i = 0; i < 64; ++i) {
            if (ei32[2 * i + 1] != 0) { is64 = 0; break; }
        }
        *flag = is64;
    }
}

// Count in-degree of each target node (int atomics into 400KB array - L2 resident).
__global__ void count_edges(const void* __restrict__ ei, const int* __restrict__ flag,
                            int* __restrict__ cnt, int E) {
    int e = blockIdx.x * blockDim.x + threadIdx.x;
    if (e >= E) return;
    int t;
    if (*flag) t = (int)((const long long*)ei)[E + e];
    else       t = ((const int*)ei)[E + e];
    atomicAdd(&cnt[t], 1);
}

// Single-block exclusive scan of cnt[M] -> rowptr[M+1] and cursor[M].
__global__ __launch_bounds__(1024)
void scan_kernel(const int* __restrict__ cnt, int* __restrict__ rowptr,
                 int* __restrict__ cursor, int M) {
    __shared__ int sums[1024];
    const int t = threadIdx.x;
    const int chunk = (M + 1023) / 1024;
    const int beg = t * chunk;
    const int end = min(beg + chunk, M);
    int s = 0;
    for (int i = beg; i < end; ++i) s += cnt[i];
    sums[t] = s;
    __syncthreads();
    for (int off = 1; off < 1024; off <<= 1) {
        int v = (t >= off) ? sums[t - off] : 0;
        __syncthreads();
        sums[t] += v;
        __syncthreads();
    }
    int prefix = (t == 0) ? 0 : sums[t - 1];
    for (int i = beg; i < end; ++i) {
        int c = cnt[i];
        rowptr[i] = prefix;
        cursor[i] = prefix;
        prefix += c;
    }
    if (t == 1023) rowptr[M] = sums[1023];
}

// Scatter edge source ids into CSR buckets (int atomics on cursor, L2 resident).
__global__ void fill_csr(const void* __restrict__ ei, const int* __restrict__ flag,
                         int* __restrict__ cursor, int* __restrict__ csr_src, int E) {
    int e = blockIdx.x * blockDim.x + threadIdx.x;
    if (e >= E) return;
    int s, t;
    if (*flag) {
        const long long* p = (const long long*)ei;
        s = (int)p[e]; t = (int)p[E + e];
    } else {
        const int* p = (const int*)ei;
        s = p[e]; t = p[E + e];
    }
    int pos = atomicAdd(&cursor[t], 1);
    csr_src[pos] = s;
}

// One wave per node: gather x[src] rows (float4, 2 edges per iteration), mean, store agg.
__global__ __launch_bounds__(256)
void gather_nodes(const float* __restrict__ x, const int* __restrict__ rowptr,
                  const int* __restrict__ csr_src, float* __restrict__ agg, int M) {
    const int wave = threadIdx.x >> 6;
    const int lane = threadIdx.x & 63;
    const int node = blockIdx.x * 4 + wave;
    if (node >= M) return;
    const int beg = rowptr[node], end = rowptr[node + 1];
    const int sub = lane >> 5;    // which edge of the pair
    const int col = lane & 31;    // float4 column (32*4 = 128 floats)
    const float4* x4 = (const float4*)x;
    float ax = 0.f, ay = 0.f, az = 0.f, aw = 0.f;
    float bx = 0.f, by = 0.f, bz = 0.f, bw = 0.f;
    int i = beg;
    for (; i + 4 <= end; i += 4) {
        int s0 = csr_src[i + sub];
        int s1 = csr_src[i + 2 + sub];
        float4 v0 = x4[(long)s0 * 32 + col];
        float4 v1 = x4[(long)s1 * 32 + col];
        ax += v0.x; ay += v0.y; az += v0.z; aw += v0.w;
        bx += v1.x; by += v1.y; bz += v1.z; bw += v1.w;
    }
    for (; i + 2 <= end; i += 2) {
        int s0 = csr_src[i + sub];
        float4 v0 = x4[(long)s0 * 32 + col];
        ax += v0.x; ay += v0.y; az += v0.z; aw += v0.w;
    }
    if (i < end && sub == 0) {
        float4 v = x4[(long)csr_src[i] * 32 + col];
        ax += v.x; ay += v.y; az += v.z; aw += v.w;
    }
    ax += bx; ay += by; az += bz; aw += bw;
    ax += __shfl_xor(ax, 32);
    ay += __shfl_xor(ay, 32);
    az += __shfl_xor(az, 32);
    aw += __shfl_xor(aw, 32);
    if (sub == 0) {
        const float rd = 1.0f / fmaxf((float)(end - beg), 1.0f);
        ((float4*)agg)[(long)node * 32 + col] = make_float4(ax * rd, ay * rd, az * rd, aw * rd);
    }
}

// Fused GEMM: C[m][j] = sum_k A[m][k]*B[j][k], A=[x | agg], B=[Wr2 | Wl2],
// then colsum_m relu(C + bias) -> atomic add into cacheline-padded pooled array.
__global__ __launch_bounds__(256)
void gemm_pool(const float* __restrict__ x, const float* __restrict__ agg,
               const float* __restrict__ Wr2, const float* __restrict__ Wl2,
               const float* __restrict__ bias2,
               float* __restrict__ pooled_pad, int M) {
    __shared__ unsigned short As[128][72];
    __shared__ unsigned short Bs[128][72];
    __shared__ float pool_l[128];

    const int tid = threadIdx.x;
    const int blk_m = blockIdx.x, blk_n = blockIdx.y;
    const long mbase = (long)blk_m * 128;

    const float4* x4   = (const float4*)x;
    const float4* agg4 = (const float4*)agg;
    const float4* wr4  = (const float4*)Wr2;
    const float4* wl4  = (const float4*)Wl2;

    const int lane = tid & 63;
    const int wave = tid >> 6;
    const int wm = wave >> 1, wn = wave & 1;
    const int lrow = lane & 15;
    const int quad = lane >> 4;

    const int sc = tid & 15;
    const int sr = tid >> 4;

    f32x4 acc[4][4] = {};

    for (int kc = 0; kc < 4; ++kc) {
        #pragma unroll
        for (int it = 0; it < 8; ++it) {
            const int rowl = sr + it * 16;
            const long m = mbase + rowl;
            float4 v = make_float4(0.f, 0.f, 0.f, 0.f);
            if (m < M) {
                v = (kc < 2) ? x4[m * 32 + kc * 16 + sc]
                             : agg4[m * 32 + (kc - 2) * 16 + sc];
            }
            *(uint2*)&As[rowl][sc * 4] = pack4(v);
            const int j = blk_n * 128 + rowl;
            float4 w = (kc < 2) ? wr4[j * 32 + kc * 16 + sc]
                                : wl4[j * 32 + (kc - 2) * 16 + sc];
            *(uint2*)&Bs[rowl][sc * 4] = pack4(w);
        }
        __syncthreads();

        #pragma unroll
        for (int ks = 0; ks < 2; ++ks) {
            const int k0 = ks * 32 + quad * 8;
            bf16x8 a[4], b[4];
            #pragma unroll
            for (int i = 0; i < 4; ++i)
                a[i] = *(const bf16x8*)&As[wm * 64 + i * 16 + lrow][k0];
            #pragma unroll
            for (int t = 0; t < 4; ++t)
                b[t] = *(const bf16x8*)&Bs[wn * 64 + t * 16 + lrow][k0];
            #pragma unroll
            for (int i = 0; i < 4; ++i)
                #pragma unroll
                for (int t = 0; t < 4; ++t)
                    acc[i][t] = __builtin_amdgcn_mfma_f32_16x16x32_bf16(a[i], b[t], acc[i][t], 0, 0, 0);
        }
        __syncthreads();
    }

    if (tid < 128) pool_l[tid] = 0.f;
    __syncthreads();

    #pragma unroll
    for (int t = 0; t < 4; ++t) {
        const int jl = wn * 64 + t * 16 + (lane & 15);
        const int jg = blk_n * 128 + jl;
        const float bv = bias2[jg];
        float s = 0.f;
        #pragma unroll
        for (int i = 0; i < 4; ++i) {
            const long rbase = mbase + wm * 64 + i * 16 + quad * 4;
            #pragma unroll
            for (int r = 0; r < 4; ++r) {
                float h = acc[i][t][r] + bv;
                h = fmaxf(h, 0.f);
                if (rbase + r < M) s += h;
            }
        }
        s += __shfl_xor(s, 16);
        s += __shfl_xor(s, 32);
        if (quad == 0) atomicAdd(&pool_l[jl], s);
    }
    __syncthreads();
    // one feature per 64B cacheline -> 256 independent atomic streams
    if (tid < 128) atomicAdd(&pooled_pad[(blk_n * 128 + tid) * 16], pool_l[tid]);
}

// pooled -> MLP head -> log_softmax. One block, 256 threads.
__global__ __launch_bounds__(256)
void head_kernel(const float* __restrict__ pooled_pad,
                 const float* __restrict__ W1, const float* __restrict__ b1,
                 const float* __restrict__ W2, const float* __restrict__ b2,
                 float* __restrict__ out, float invM) {
    __shared__ float pooled_s[256];
    __shared__ float z1_s[256];
    __shared__ float z2_s[10];
    const int j = threadIdx.x;

    pooled_s[j] = pooled_pad[j * 16] * invM;
    __syncthreads();

    const float4* w4 = (const float4*)(W1 + (long)j * 256);
    float sx = 0.f, sy = 0.f, sz = 0.f, sw = 0.f;
    #pragma unroll 8
    for (int k = 0; k < 64; ++k) {
        float4 w = w4[k];
        float4 p = *(const float4*)&pooled_s[k * 4];
        sx += w.x * p.x; sy += w.y * p.y; sz += w.z * p.z; sw += w.w * p.w;
    }
    z1_s[j] = fmaxf(b1[j] + sx + sy + sz + sw, 0.f);
    __syncthreads();

    if (j < 160) {
        const int c = j >> 4, q = j & 15;
        float s = 0.f;
        for (int k = q; k < 256; k += 16) s += W2[c * 256 + k] * z1_s[k];
        #pragma unroll
        for (int off = 8; off >= 1; off >>= 1) s += __shfl_down(s, off, 16);
        if (q == 0) z2_s[c] = s + b2[c];
    }
    __syncthreads();

    if (j == 0) {
        float mx = z2_s[0];
        for (int c = 1; c < 10; ++c) mx = fmaxf(mx, z2_s[c]);
        float se = 0.f;
        for (int c = 0; c < 10; ++c) se += expf(z2_s[c] - mx);
        const float ls = logf(se);
        for (int c = 0; c < 10; ++c) out[c] = z2_s[c] - mx - ls;
    }
}

extern "C" void kernel_launch(void* const* d_in, const int* in_sizes, int n_in,
                              void* d_out, int out_size, void* d_ws, size_t ws_size,
                              hipStream_t stream) {
    const float* x    = (const float*)d_in[0];
    const void*  ei   = d_in[1];
    const float* Wl   = (const float*)d_in[2];
    const float* Wr   = (const float*)d_in[3];
    const float* bias = (const float*)d_in[4];
    const float* W1   = (const float*)d_in[5];
    const float* b1   = (const float*)d_in[6];
    const float* W2   = (const float*)d_in[7];
    const float* b2   = (const float*)d_in[8];
    float* out = (float*)d_out;

    const int M = in_sizes[0] / D_IN;       // 100000 nodes
    const int E = in_sizes[1] / 2;          // 1.6M edges
    const int L = in_sizes[4] / D_HID;      // 3 layers
    const int NMB = (M + 127) / 128;

    // Only the LAST layer matters (h is overwritten each loop iteration).
    const float* Wl2   = Wl + (long)(L - 1) * D_HID * D_IN;
    const float* Wr2   = Wr + (long)(L - 1) * D_HID * D_IN;
    const float* bias2 = bias + (long)(L - 1) * D_HID;

    // workspace: agg[M*128]f | pooled_pad[256*16]f | cnt[M]i | rowptr[M+1]i
    //            | cursor[M]i | csr[E]i | flag i
    float* ws         = (float*)d_ws;
    float* agg        = ws;
    float* pooled_pad = agg + (long)M * D_IN;
    int*   cnt        = (int*)(pooled_pad + 256 * 16);
    int*   rowptr     = cnt + M;
    int*   cursor     = rowptr + M + 1;
    int*   csr        = cursor + M;
    int*   flag       = csr + E;

    detect_idx_dtype<<<1, 64, 0, stream>>>((const int*)ei, flag);
    hipMemsetAsync(cnt, 0, (size_t)M * sizeof(int), stream);
    hipMemsetAsync(pooled_pad, 0, 256 * 16 * sizeof(float), stream);

    count_edges<<<(E + 255) / 256, 256, 0, stream>>>(ei, flag, cnt, E);
    scan_kernel<<<1, 1024, 0, stream>>>(cnt, rowptr, cursor, M);
    fill_csr<<<(E + 255) / 256, 256, 0, stream>>>(ei, flag, cursor, csr, E);
    gather_nodes<<<(M + 3) / 4, 256, 0, stream>>>(x, rowptr, csr, agg, M);

    dim3 g(NMB, 2);
    gemm_pool<<<g, 256, 0, stream>>>(x, agg, Wr2, Wl2, bias2, pooled_pad, M);

    head_kernel<<<1, 256, 0, stream>>>(pooled_pad, W1, b1, W2, b2, out, 1.0f / (float)M);
}

// Round 4
// 505.929 us; speedup vs baseline: 6.2465x; 1.4096x over previous
//
#include <hip/hip_runtime.h>
#include <hip/hip_bf16.h>

#define D_IN  128
#define D_HID 256

typedef __bf16 bf16x8 __attribute__((ext_vector_type(8)));
typedef float  f32x4  __attribute__((ext_vector_type(4)));

__device__ __forceinline__ unsigned short f2bf(float f) {
    unsigned u = __float_as_uint(f);
    u += 0x7FFFu + ((u >> 16) & 1u);   // RNE
    return (unsigned short)(u >> 16);
}
__device__ __forceinline__ uint2 pack4(float4 v) {
    unsigned lo = (unsigned)f2bf(v.x) | ((unsigned)f2bf(v.y) << 16);
    unsigned hi = (unsigned)f2bf(v.z) | ((unsigned)f2bf(v.w) << 16);
    return make_uint2(lo, hi);
}

// Detect whether edge_index is int64 (hi dwords of first 64 entries all zero) or int32.
__global__ void detect_idx_dtype(const int* __restrict__ ei32, int* __restrict__ flag) {
    if (threadIdx.x == 0 && blockIdx.x == 0) {
        int is64 = 1;
        for (int i = 0; i < 64; ++i) {
            if (ei32[2 * i + 1] != 0) { is64 = 0; break; }
        }
        *flag = is64;
    }
}

// Count in-degree of each target node (int atomics into 400KB array - L2 resident).
__global__ void count_edges(const void* __restrict__ ei, const int* __restrict__ flag,
                            int* __restrict__ cnt, int E) {
    int e = blockIdx.x * blockDim.x + threadIdx.x;
    if (e >= E) return;
    int t;
    if (*flag) t = (int)((const long long*)ei)[E + e];
    else       t = ((const int*)ei)[E + e];
    atomicAdd(&cnt[t], 1);
}

// ---- 3-phase hierarchical exclusive scan of cnt[M] -> rowptr[M+1], cursor[M] ----
// Phase 1: per-block (2048 elements) reduction -> bsum[NB]
__global__ __launch_bounds__(256)
void scan_p1(const int* __restrict__ cnt, int* __restrict__ bsum, int M) {
    __shared__ int red[256];
    const int t = threadIdx.x;
    const long base = (long)blockIdx.x * 2048 + (long)t * 8;
    int s = 0;
    if (base + 8 <= M) {
        int4 a = *(const int4*)&cnt[base];
        int4 b = *(const int4*)&cnt[base + 4];
        s = a.x + a.y + a.z + a.w + b.x + b.y + b.z + b.w;
    } else {
        for (int i = 0; i < 8; ++i) if (base + i < M) s += cnt[base + i];
    }
    red[t] = s;
    __syncthreads();
    for (int off = 128; off > 0; off >>= 1) {
        if (t < off) red[t] += red[t + off];
        __syncthreads();
    }
    if (t == 0) bsum[blockIdx.x] = red[0];
}

// Phase 2: scan the NB block sums (NB <= 1024) -> exclusive offsets, write rowptr[M]=total.
__global__ __launch_bounds__(1024)
void scan_p2(const int* __restrict__ bsum, int* __restrict__ boff,
             int* __restrict__ rowptr, int M, int NB) {
    __shared__ int s[1024];
    const int t = threadIdx.x;
    int v = (t < NB) ? bsum[t] : 0;
    s[t] = v;
    __syncthreads();
    for (int off = 1; off < 1024; off <<= 1) {
        int u = (t >= off) ? s[t - off] : 0;
        __syncthreads();
        s[t] += u;
        __syncthreads();
    }
    if (t < NB) boff[t] = s[t] - v;
    if (t == NB - 1) rowptr[M] = s[t];
}

// Phase 3: per-block local scan + offset -> rowptr/cursor.
__global__ __launch_bounds__(256)
void scan_p3(const int* __restrict__ cnt, const int* __restrict__ boff,
             int* __restrict__ rowptr, int* __restrict__ cursor, int M) {
    __shared__ int tsum[256];
    const int t = threadIdx.x;
    const long base = (long)blockIdx.x * 2048 + (long)t * 8;
    int v[8];
    int s = 0;
    #pragma unroll
    for (int i = 0; i < 8; ++i) {
        v[i] = (base + i < M) ? cnt[base + i] : 0;
        s += v[i];
    }
    tsum[t] = s;
    __syncthreads();
    for (int off = 1; off < 256; off <<= 1) {
        int u = (t >= off) ? tsum[t - off] : 0;
        __syncthreads();
        tsum[t] += u;
        __syncthreads();
    }
    int prefix = boff[blockIdx.x] + tsum[t] - s;   // exclusive prefix for this thread
    #pragma unroll
    for (int i = 0; i < 8; ++i) {
        if (base + i < M) { rowptr[base + i] = prefix; cursor[base + i] = prefix; }
        prefix += v[i];
    }
}

// Scatter edge source ids into CSR buckets (int atomics on cursor, L2 resident).
__global__ void fill_csr(const void* __restrict__ ei, const int* __restrict__ flag,
                         int* __restrict__ cursor, int* __restrict__ csr_src, int E) {
    int e = blockIdx.x * blockDim.x + threadIdx.x;
    if (e >= E) return;
    int s, t;
    if (*flag) {
        const long long* p = (const long long*)ei;
        s = (int)p[e]; t = (int)p[E + e];
    } else {
        const int* p = (const int*)ei;
        s = p[e]; t = p[E + e];
    }
    int pos = atomicAdd(&cursor[t], 1);
    csr_src[pos] = s;
}

// One wave per node: gather x[src] rows (float4, 2 edges per iteration), mean, store agg.
__global__ __launch_bounds__(256)
void gather_nodes(const float* __restrict__ x, const int* __restrict__ rowptr,
                  const int* __restrict__ csr_src, float* __restrict__ agg, int M) {
    const int wave = threadIdx.x >> 6;
    const int lane = threadIdx.x & 63;
    const int node = blockIdx.x * 4 + wave;
    if (node >= M) return;
    const int beg = rowptr[node], end = rowptr[node + 1];
    const int sub = lane >> 5;    // which edge of the pair
    const int col = lane & 31;    // float4 column (32*4 = 128 floats)
    const float4* x4 = (const float4*)x;
    float ax = 0.f, ay = 0.f, az = 0.f, aw = 0.f;
    float bx = 0.f, by = 0.f, bz = 0.f, bw = 0.f;
    int i = beg;
    for (; i + 4 <= end; i += 4) {
        int s0 = csr_src[i + sub];
        int s1 = csr_src[i + 2 + sub];
        float4 v0 = x4[(long)s0 * 32 + col];
        float4 v1 = x4[(long)s1 * 32 + col];
        ax += v0.x; ay += v0.y; az += v0.z; aw += v0.w;
        bx += v1.x; by += v1.y; bz += v1.z; bw += v1.w;
    }
    for (; i + 2 <= end; i += 2) {
        int s0 = csr_src[i + sub];
        float4 v0 = x4[(long)s0 * 32 + col];
        ax += v0.x; ay += v0.y; az += v0.z; aw += v0.w;
    }
    if (i < end && sub == 0) {
        float4 v = x4[(long)csr_src[i] * 32 + col];
        ax += v.x; ay += v.y; az += v.z; aw += v.w;
    }
    ax += bx; ay += by; az += bz; aw += bw;
    ax += __shfl_xor(ax, 32);
    ay += __shfl_xor(ay, 32);
    az += __shfl_xor(az, 32);
    aw += __shfl_xor(aw, 32);
    if (sub == 0) {
        const float rd = 1.0f / fmaxf((float)(end - beg), 1.0f);
        ((float4*)agg)[(long)node * 32 + col] = make_float4(ax * rd, ay * rd, az * rd, aw * rd);
    }
}

// Fused GEMM: C[m][j] = sum_k A[m][k]*B[j][k], A=[x | agg], B=[Wr2 | Wl2],
// then colsum_m relu(C + bias) -> atomic add into cacheline-padded pooled array.
__global__ __launch_bounds__(256)
void gemm_pool(const float* __restrict__ x, const float* __restrict__ agg,
               const float* __restrict__ Wr2, const float* __restrict__ Wl2,
               const float* __restrict__ bias2,
               float* __restrict__ pooled_pad, int M) {
    __shared__ unsigned short As[128][72];
    __shared__ unsigned short Bs[128][72];
    __shared__ float pool_l[128];

    const int tid = threadIdx.x;
    const int blk_m = blockIdx.x, blk_n = blockIdx.y;
    const long mbase = (long)blk_m * 128;

    const float4* x4   = (const float4*)x;
    const float4* agg4 = (const float4*)agg;
    const float4* wr4  = (const float4*)Wr2;
    const float4* wl4  = (const float4*)Wl2;

    const int lane = tid & 63;
    const int wave = tid >> 6;
    const int wm = wave >> 1, wn = wave & 1;
    const int lrow = lane & 15;
    const int quad = lane >> 4;

    const int sc = tid & 15;
    const int sr = tid >> 4;

    f32x4 acc[4][4] = {};

    for (int kc = 0; kc < 4; ++kc) {
        #pragma unroll
        for (int it = 0; it < 8; ++it) {
            const int rowl = sr + it * 16;
            const long m = mbase + rowl;
            float4 v = make_float4(0.f, 0.f, 0.f, 0.f);
            if (m < M) {
                v = (kc < 2) ? x4[m * 32 + kc * 16 + sc]
                             : agg4[m * 32 + (kc - 2) * 16 + sc];
            }
            *(uint2*)&As[rowl][sc * 4] = pack4(v);
            const int j = blk_n * 128 + rowl;
            float4 w = (kc < 2) ? wr4[j * 32 + kc * 16 + sc]
                                : wl4[j * 32 + (kc - 2) * 16 + sc];
            *(uint2*)&Bs[rowl][sc * 4] = pack4(w);
        }
        __syncthreads();

        #pragma unroll
        for (int ks = 0; ks < 2; ++ks) {
            const int k0 = ks * 32 + quad * 8;
            bf16x8 a[4], b[4];
            #pragma unroll
            for (int i = 0; i < 4; ++i)
                a[i] = *(const bf16x8*)&As[wm * 64 + i * 16 + lrow][k0];
            #pragma unroll
            for (int t = 0; t < 4; ++t)
                b[t] = *(const bf16x8*)&Bs[wn * 64 + t * 16 + lrow][k0];
            #pragma unroll
            for (int i = 0; i < 4; ++i)
                #pragma unroll
                for (int t = 0; t < 4; ++t)
                    acc[i][t] = __builtin_amdgcn_mfma_f32_16x16x32_bf16(a[i], b[t], acc[i][t], 0, 0, 0);
        }
        __syncthreads();
    }

    if (tid < 128) pool_l[tid] = 0.f;
    __syncthreads();

    #pragma unroll
    for (int t = 0; t < 4; ++t) {
        const int jl = wn * 64 + t * 16 + (lane & 15);
        const int jg = blk_n * 128 + jl;
        const float bv = bias2[jg];
        float s = 0.f;
        #pragma unroll
        for (int i = 0; i < 4; ++i) {
            const long rbase = mbase + wm * 64 + i * 16 + quad * 4;
            #pragma unroll
            for (int r = 0; r < 4; ++r) {
                float h = acc[i][t][r] + bv;
                h = fmaxf(h, 0.f);
                if (rbase + r < M) s += h;
            }
        }
        s += __shfl_xor(s, 16);
        s += __shfl_xor(s, 32);
        if (quad == 0) atomicAdd(&pool_l[jl], s);
    }
    __syncthreads();
    // one feature per 64B cacheline -> 256 independent atomic streams
    if (tid < 128) atomicAdd(&pooled_pad[(blk_n * 128 + tid) * 16], pool_l[tid]);
}

// pooled -> MLP head -> log_softmax. One block, 256 threads.
__global__ __launch_bounds__(256)
void head_kernel(const float* __restrict__ pooled_pad,
                 const float* __restrict__ W1, const float* __restrict__ b1,
                 const float* __restrict__ W2, const float* __restrict__ b2,
                 float* __restrict__ out, float invM) {
    __shared__ float pooled_s[256];
    __shared__ float z1_s[256];
    __shared__ float z2_s[10];
    const int j = threadIdx.x;

    pooled_s[j] = pooled_pad[j * 16] * invM;
    __syncthreads();

    const float4* w4 = (const float4*)(W1 + (long)j * 256);
    float sx = 0.f, sy = 0.f, sz = 0.f, sw = 0.f;
    #pragma unroll 8
    for (int k = 0; k < 64; ++k) {
        float4 w = w4[k];
        float4 p = *(const float4*)&pooled_s[k * 4];
        sx += w.x * p.x; sy += w.y * p.y; sz += w.z * p.z; sw += w.w * p.w;
    }
    z1_s[j] = fmaxf(b1[j] + sx + sy + sz + sw, 0.f);
    __syncthreads();

    if (j < 160) {
        const int c = j >> 4, q = j & 15;
        float s = 0.f;
        for (int k = q; k < 256; k += 16) s += W2[c * 256 + k] * z1_s[k];
        #pragma unroll
        for (int off = 8; off >= 1; off >>= 1) s += __shfl_down(s, off, 16);
        if (q == 0) z2_s[c] = s + b2[c];
    }
    __syncthreads();

    if (j == 0) {
        float mx = z2_s[0];
        for (int c = 1; c < 10; ++c) mx = fmaxf(mx, z2_s[c]);
        float se = 0.f;
        for (int c = 0; c < 10; ++c) se += expf(z2_s[c] - mx);
        const float ls = logf(se);
        for (int c = 0; c < 10; ++c) out[c] = z2_s[c] - mx - ls;
    }
}

extern "C" void kernel_launch(void* const* d_in, const int* in_sizes, int n_in,
                              void* d_out, int out_size, void* d_ws, size_t ws_size,
                              hipStream_t stream) {
    const float* x    = (const float*)d_in[0];
    const void*  ei   = d_in[1];
    const float* Wl   = (const float*)d_in[2];
    const float* Wr   = (const float*)d_in[3];
    const float* bias = (const float*)d_in[4];
    const float* W1   = (const float*)d_in[5];
    const float* b1   = (const float*)d_in[6];
    const float* W2   = (const float*)d_in[7];
    const float* b2   = (const float*)d_in[8];
    float* out = (float*)d_out;

    const int M = in_sizes[0] / D_IN;       // 100000 nodes
    const int E = in_sizes[1] / 2;          // 1.6M edges
    const int L = in_sizes[4] / D_HID;      // 3 layers
    const int NMB = (M + 127) / 128;
    const int NSB = (M + 2047) / 2048;      // scan blocks (49)

    // Only the LAST layer matters (h is overwritten each loop iteration).
    const float* Wl2   = Wl + (long)(L - 1) * D_HID * D_IN;
    const float* Wr2   = Wr + (long)(L - 1) * D_HID * D_IN;
    const float* bias2 = bias + (long)(L - 1) * D_HID;

    // workspace: agg[M*128]f | pooled_pad[256*16]f | cnt[M]i | rowptr[M+1]i
    //            | cursor[M]i | csr[E]i | bsum[NSB]i | boff[NSB]i | flag i
    float* ws         = (float*)d_ws;
    float* agg        = ws;
    float* pooled_pad = agg + (long)M * D_IN;
    int*   cnt        = (int*)(pooled_pad + 256 * 16);
    int*   rowptr     = cnt + M;
    int*   cursor     = rowptr + M + 1;
    int*   csr        = cursor + M;
    int*   bsum       = csr + E;
    int*   boff       = bsum + NSB;
    int*   flag       = boff + NSB;

    detect_idx_dtype<<<1, 64, 0, stream>>>((const int*)ei, flag);
    hipMemsetAsync(cnt, 0, (size_t)M * sizeof(int), stream);
    hipMemsetAsync(pooled_pad, 0, 256 * 16 * sizeof(float), stream);

    count_edges<<<(E + 255) / 256, 256, 0, stream>>>(ei, flag, cnt, E);
    scan_p1<<<NSB, 256, 0, stream>>>(cnt, bsum, M);
    scan_p2<<<1, 1024, 0, stream>>>(bsum, boff, rowptr, M, NSB);
    scan_p3<<<NSB, 256, 0, stream>>>(cnt, boff, rowptr, cursor, M);
    fill_csr<<<(E + 255) / 256, 256, 0, stream>>>(ei, flag, cursor, csr, E);
    gather_nodes<<<(M + 3) / 4, 256, 0, stream>>>(x, rowptr, csr, agg, M);

    dim3 g(NMB, 2);
    gemm_pool<<<g, 256, 0, stream>>>(x, agg, Wr2, Wl2, bias2, pooled_pad, M);

    head_kernel<<<1, 256, 0, stream>>>(pooled_pad, W1, b1, W2, b2, out, 1.0f / (float)M);
}